// Round 1
// baseline (80.706 us; speedup 1.0000x reference)
//
#include <hip/hip_runtime.h>
#include <hip/hip_bf16.h>

// QuantumFeedForward: analytic collapse of the 10-qubit circuit.
// q[n,w] = prod_{v in M_w} cos(theta_v)*cos(x[n,v]); out = relu(q@W1^T+b1)@W2^T+b2.

typedef __attribute__((ext_vector_type(8))) short bf16x8;     // 8 bf16 = 4 VGPR (MFMA operand)
typedef __attribute__((ext_vector_type(4))) float f32x4;      // MFMA accumulator
typedef __attribute__((ext_vector_type(8))) unsigned short us8;
typedef __attribute__((ext_vector_type(4))) unsigned short us4;

#define NTOK  16384
#define EMBED 512
#define FFN   2048
#define NQ    10

__device__ __forceinline__ unsigned short f2bf(float f) {
  union { float f; unsigned int u; } a; a.f = f;
  unsigned int r = a.u + 0x7FFFu + ((a.u >> 16) & 1u);   // RNE
  return (unsigned short)(r >> 16);
}

__device__ __forceinline__ void gload_lds16(const void* g, void* l) {
  __builtin_amdgcn_global_load_lds(
      (const __attribute__((address_space(1))) unsigned int*)g,
      (__attribute__((address_space(3))) unsigned int*)l, 16, 0, 0);
}

// ---------------- K0: W2 (512x2048 f32) -> bf16 ----------------
__global__ __launch_bounds__(256) void k_cvt_w2(const float* __restrict__ W2,
                                                unsigned short* __restrict__ W2b) {
  int i = (blockIdx.x * 256 + threadIdx.x) * 4;   // grid covers exactly 512*2048
  float4 v = *(const float4*)(W2 + i);
  us4 o;
  o[0] = f2bf(v.x); o[1] = f2bf(v.y); o[2] = f2bf(v.z); o[3] = f2bf(v.w);
  *(us4*)(W2b + i) = o;
}

// ---------------- K1: H = relu(q@W1^T + b1) in bf16 ----------------
// 32 tokens per block, 256 threads; thread t owns FFN cols t*8..t*8+7 (W1 rows in regs).
__global__ __launch_bounds__(256) void k_phase1(const float* __restrict__ x,
                                                const float* __restrict__ theta,
                                                const float* __restrict__ W1,
                                                const float* __restrict__ b1,
                                                unsigned short* __restrict__ Hb) {
  __shared__ float qs[32][12];   // padded to 48B rows for aligned float4 reads
  const int tid = threadIdx.x;
  const int tok0 = blockIdx.x * 32;
  const int k0 = tid * 8;

  float w1r[8][NQ];
  float b1r[8];
#pragma unroll
  for (int j = 0; j < 8; ++j) {
    b1r[j] = b1[k0 + j];
#pragma unroll
    for (int w = 0; w < NQ; ++w) w1r[j][w] = W1[(k0 + j) * NQ + w];
  }

  if (tid < 32) {
    const int masks[NQ] = {0x2AB,0x3FD,0x3FA,0x3F5,0x3EA,0x3D5,0x3AA,0x355,0x2AA,0x155};
    int token = tok0 + tid;
    float z[NQ];
#pragma unroll
    for (int w = 0; w < NQ; ++w)
      z[w] = __builtin_cosf(x[(size_t)token * EMBED + w]) * __builtin_cosf(theta[w]);
#pragma unroll
    for (int w = 0; w < NQ; ++w) {
      float p = 1.f;
#pragma unroll
      for (int v = 0; v < NQ; ++v)
        if ((masks[w] >> v) & 1) p *= z[v];
      qs[tid][w] = p;
    }
  }
  __syncthreads();

  for (int t = 0; t < 32; ++t) {
    float4 q0 = *(const float4*)&qs[t][0];
    float4 q1 = *(const float4*)&qs[t][4];
    float2 q2 = *(const float2*)&qs[t][8];
    us8 o;
#pragma unroll
    for (int j = 0; j < 8; ++j) {
      float s = b1r[j];
      s += q0.x * w1r[j][0] + q0.y * w1r[j][1] + q0.z * w1r[j][2] + q0.w * w1r[j][3];
      s += q1.x * w1r[j][4] + q1.y * w1r[j][5] + q1.z * w1r[j][6] + q1.w * w1r[j][7];
      s += q2.x * w1r[j][8] + q2.y * w1r[j][9];
      s = fmaxf(s, 0.f);
      o[j] = f2bf(s);
    }
    *(us8*)&Hb[(size_t)(tok0 + t) * FFN + k0] = o;   // 16B coalesced
  }
}

// ---------------- K2: out = Hb @ W2b^T + b2 (m97-style 128x128x32 MFMA) ----------------
#define BM 128
#define BN 128
#define BK 32
__global__ __launch_bounds__(256) void k_gemm(const unsigned short* __restrict__ Hb,
                                              const unsigned short* __restrict__ W2b,
                                              const float* __restrict__ b2,
                                              float* __restrict__ out) {
  // XCD-aware swizzle: 512 blocks, 64 consecutive per XCD -> same-mb groups share L2.
  int bid = blockIdx.x;
  int swz = (bid & 7) * 64 + (bid >> 3);
  const int m0 = (swz >> 2) * BM;
  const int n0 = (swz & 3) * BN;
  const int tid = threadIdx.x;
  const int wave = tid >> 6, lane = tid & 63;
  const int wr = wave >> 1, wc = wave & 1;

  __shared__ short As[BM * BK];   // [row][k] linear, row stride 64B
  __shared__ short Bs[BN * BK];

  f32x4 acc[4][4] = {};

  const int srow = wave * 16 + (lane >> 2);    // staging row within 64-row chunk
  const int sseg = (lane & 3) * 8;             // 8 bf16 = 16B segment along k

  for (int kt = 0; kt < FFN / BK; ++kt) {
    const int k0 = kt * BK;
#pragma unroll
    for (int it = 0; it < 2; ++it) {
      gload_lds16(&Hb[(size_t)(m0 + it * 64 + srow) * FFN + k0 + sseg],
                  &As[(it * 64 + wave * 16) * BK]);
      gload_lds16(&W2b[(size_t)(n0 + it * 64 + srow) * FFN + k0 + sseg],
                  &Bs[(it * 64 + wave * 16) * BK]);
    }
    __syncthreads();   // compiler drains vmcnt before s_barrier

    bf16x8 af[4], bg[4];
#pragma unroll
    for (int i = 0; i < 4; ++i)
      af[i] = *(const bf16x8*)&As[(wr * 64 + i * 16 + (lane & 15)) * BK + (lane >> 4) * 8];
#pragma unroll
    for (int j = 0; j < 4; ++j)
      bg[j] = *(const bf16x8*)&Bs[(wc * 64 + j * 16 + (lane & 15)) * BK + (lane >> 4) * 8];
#pragma unroll
    for (int i = 0; i < 4; ++i)
#pragma unroll
      for (int j = 0; j < 4; ++j)
        acc[i][j] = __builtin_amdgcn_mfma_f32_16x16x32_bf16(af[i], bg[j], acc[i][j], 0, 0, 0);
    __syncthreads();
  }

#pragma unroll
  for (int i = 0; i < 4; ++i) {
    const int row = m0 + wr * 64 + i * 16 + (lane >> 4) * 4;
#pragma unroll
    for (int j = 0; j < 4; ++j) {
      const int col = n0 + wc * 64 + j * 16 + (lane & 15);
      const float bb = b2[col];
#pragma unroll
      for (int r = 0; r < 4; ++r)
        out[(size_t)(row + r) * EMBED + col] = acc[i][j][r] + bb;
    }
  }
}

extern "C" void kernel_launch(void* const* d_in, const int* in_sizes, int n_in,
                              void* d_out, int out_size, void* d_ws, size_t ws_size,
                              hipStream_t stream) {
  const float* x     = (const float*)d_in[0];
  const float* theta = (const float*)d_in[1];
  const float* W1    = (const float*)d_in[2];
  const float* b1    = (const float*)d_in[3];
  const float* W2    = (const float*)d_in[4];
  const float* b2    = (const float*)d_in[5];
  float* out = (float*)d_out;

  char* ws = (char*)d_ws;
  unsigned short* W2b = (unsigned short*)ws;                       // 512*2048*2 = 2 MB
  unsigned short* Hb  = (unsigned short*)(ws + (2u << 20));        // 16384*2048*2 = 64 MB

  k_cvt_w2<<<(EMBED * FFN) / (256 * 4), 256, 0, stream>>>(W2, W2b);
  k_phase1<<<NTOK / 32, 256, 0, stream>>>(x, theta, W1, b1, Hb);
  k_gemm<<<(NTOK / BM) * (EMBED / BN), 256, 0, stream>>>(Hb, W2b, b2, out);
}

// Round 2
// 78.177 us; speedup vs baseline: 1.0324x; 1.0324x over previous
//
#include <hip/hip_runtime.h>
#include <hip/hip_bf16.h>

// QuantumFeedForward: analytic collapse of the 10-qubit circuit.
// q[n,w] = prod_{v in M_w} cos(theta_v)*cos(x[n,v]); out = relu(q@W1^T+b1)@W2^T+b2.
// Hb / W2b are stored CHUNK-SWIZZLED in global: 16B chunk c of row r lives at
// physical chunk (c&~7)|((c&7)^(r&7)), so linear global_load_lds staging yields a
// bank-conflict-free XOR-swizzled LDS tile (T2, both-sides rule #21).

typedef __attribute__((ext_vector_type(8))) short bf16x8;
typedef __attribute__((ext_vector_type(4))) float f32x4;
typedef __attribute__((ext_vector_type(8))) unsigned short us8;

#define NTOK  16384
#define EMBED 512
#define FFN   2048
#define NQ    10

__device__ __forceinline__ unsigned short f2bf(float f) {
  union { float f; unsigned int u; } a; a.f = f;
  unsigned int r = a.u + 0x7FFFu + ((a.u >> 16) & 1u);   // RNE
  return (unsigned short)(r >> 16);
}

__device__ __forceinline__ void gload_lds16(const void* g, void* l) {
  __builtin_amdgcn_global_load_lds(
      (const __attribute__((address_space(1))) unsigned int*)g,
      (__attribute__((address_space(3))) unsigned int*)l, 16, 0, 0);
}

// ---------------- K0: W2 (512x2048 f32) -> bf16, chunk-swizzled ----------------
__global__ __launch_bounds__(256) void k_cvt_w2(const float* __restrict__ W2,
                                                unsigned short* __restrict__ W2b) {
  int gid = blockIdx.x * 256 + threadIdx.x;     // one 16B chunk (8 f32 -> 8 bf16)
  int idx = gid * 8;
  int row = idx >> 11;                          // /2048
  int c   = (idx >> 3) & 255;                   // chunk within row
  int sc  = (c & ~7) | ((c & 7) ^ (row & 7));   // swizzled chunk
  float4 v0 = *(const float4*)(W2 + idx);
  float4 v1 = *(const float4*)(W2 + idx + 4);
  us8 o;
  o[0] = f2bf(v0.x); o[1] = f2bf(v0.y); o[2] = f2bf(v0.z); o[3] = f2bf(v0.w);
  o[4] = f2bf(v1.x); o[5] = f2bf(v1.y); o[6] = f2bf(v1.z); o[7] = f2bf(v1.w);
  *(us8*)(W2b + (size_t)row * FFN + sc * 8) = o;
}

// ---------------- K1: H = relu(q@W1^T + b1) bf16, chunk-swizzled ----------------
// 16 tokens/block (1024 blocks = 4/CU), thread t owns FFN cols t*8..t*8+7.
__global__ __launch_bounds__(256) void k_phase1(const float* __restrict__ x,
                                                const float* __restrict__ theta,
                                                const float* __restrict__ W1,
                                                const float* __restrict__ b1,
                                                unsigned short* __restrict__ Hb) {
  __shared__ float qs[16][12];
  const int tid = threadIdx.x;
  const int tok0 = blockIdx.x * 16;
  const int k0 = tid * 8;

  float w1r[8][NQ];
  float b1r[8];
#pragma unroll
  for (int j = 0; j < 8; ++j) {
    b1r[j] = b1[k0 + j];
#pragma unroll
    for (int w = 0; w < NQ; ++w) w1r[j][w] = W1[(k0 + j) * NQ + w];
  }

  if (tid < 16) {
    const int masks[NQ] = {0x2AB,0x3FD,0x3FA,0x3F5,0x3EA,0x3D5,0x3AA,0x355,0x2AA,0x155};
    int token = tok0 + tid;
    float z[NQ];
#pragma unroll
    for (int w = 0; w < NQ; ++w)
      z[w] = __builtin_cosf(x[(size_t)token * EMBED + w]) * __builtin_cosf(theta[w]);
#pragma unroll
    for (int w = 0; w < NQ; ++w) {
      float p = 1.f;
#pragma unroll
      for (int v = 0; v < NQ; ++v)
        if ((masks[w] >> v) & 1) p *= z[v];
      qs[tid][w] = p;
    }
  }
  __syncthreads();

  const int cbase = k0 >> 3;                     // this thread's chunk index (== tid)
  for (int t = 0; t < 16; ++t) {
    float4 q0 = *(const float4*)&qs[t][0];
    float4 q1 = *(const float4*)&qs[t][4];
    float2 q2 = *(const float2*)&qs[t][8];
    us8 o;
#pragma unroll
    for (int j = 0; j < 8; ++j) {
      float s = b1r[j];
      s += q0.x * w1r[j][0] + q0.y * w1r[j][1] + q0.z * w1r[j][2] + q0.w * w1r[j][3];
      s += q1.x * w1r[j][4] + q1.y * w1r[j][5] + q1.z * w1r[j][6] + q1.w * w1r[j][7];
      s += q2.x * w1r[j][8] + q2.y * w1r[j][9];
      s = fmaxf(s, 0.f);
      o[j] = f2bf(s);
    }
    int tok = tok0 + t;
    int sc = (cbase & ~7) | ((cbase & 7) ^ (tok & 7));
    *(us8*)&Hb[(size_t)tok * FFN + sc * 8] = o;  // 16B store, 128B-group coalesced
  }
}

// ---------------- K2: out = H @ W2^T + b2 (128x128xBK64, dbuf 2-phase) ----------------
#define BM 128
#define BN 128
#define BK 64
#define NT (FFN / BK)   // 32
__global__ __launch_bounds__(256) void k_gemm(const unsigned short* __restrict__ Hb,
                                              const unsigned short* __restrict__ W2b,
                                              const float* __restrict__ b2,
                                              float* __restrict__ out) {
  // XCD-aware swizzle: 512 blocks, 64 consecutive per XCD; nb iterates fastest.
  int bid = blockIdx.x;
  int swz = (bid & 7) * 64 + (bid >> 3);
  const int m0 = (swz >> 2) * BM;
  const int n0 = (swz & 3) * BN;
  const int tid = threadIdx.x;
  const int lane = tid & 63;
  const int wr = (tid >> 6) >> 1, wc = (tid >> 6) & 1;

  __shared__ short As[2][BM * BK];   // [row][64] rows of 128B, content pre-swizzled
  __shared__ short Bs[2][BN * BK];

  f32x4 acc[4][4] = {};

  for (int kt = 0; kt < NT + 1; ++kt) {
    // STAGE tile kt into buf (kt&1); prologue stages kt=0, then each iter
    // prefetches kt while computing kt-1.
    if (kt < NT) {
      const int buf = kt & 1;
#pragma unroll
      for (int p = 0; p < 4; ++p) {
        int chunk = p * 256 + tid;               // 1024 chunks = 128 rows x 8 slots
        int row = chunk >> 3, slot = chunk & 7;
        gload_lds16(&Hb[(size_t)(m0 + row) * FFN + kt * BK + slot * 8],
                    &As[buf][chunk * 8]);
        gload_lds16(&W2b[(size_t)(n0 + row) * FFN + kt * BK + slot * 8],
                    &Bs[buf][chunk * 8]);
      }
    }
    if (kt > 0) {
      const int buf = (kt - 1) & 1;
#pragma unroll
      for (int kk = 0; kk < 2; ++kk) {
        bf16x8 af[4], bg[4];
#pragma unroll
        for (int i = 0; i < 4; ++i) {
          int row = wr * 64 + i * 16 + (lane & 15);
          int slot = (kk * 4 + (lane >> 4)) ^ (row & 7);
          af[i] = *(const bf16x8*)&As[buf][row * BK + slot * 8];
        }
#pragma unroll
        for (int j = 0; j < 4; ++j) {
          int row = wc * 64 + j * 16 + (lane & 15);
          int slot = (kk * 4 + (lane >> 4)) ^ (row & 7);
          bg[j] = *(const bf16x8*)&Bs[buf][row * BK + slot * 8];
        }
#pragma unroll
        for (int i = 0; i < 4; ++i)
#pragma unroll
          for (int j = 0; j < 4; ++j)
            acc[i][j] = __builtin_amdgcn_mfma_f32_16x16x32_bf16(af[i], bg[j], acc[i][j], 0, 0, 0);
      }
    }
    __syncthreads();   // drains this iter's STAGE (vmcnt) + LDS reads; 1 barrier/K-tile
  }

#pragma unroll
  for (int i = 0; i < 4; ++i) {
    const int row = m0 + wr * 64 + i * 16 + (lane >> 4) * 4;
#pragma unroll
    for (int j = 0; j < 4; ++j) {
      const int col = n0 + wc * 64 + j * 16 + (lane & 15);
      const float bb = b2[col];
#pragma unroll
      for (int r = 0; r < 4; ++r)
        out[(size_t)(row + r) * EMBED + col] = acc[i][j][r] + bb;
    }
  }
}

extern "C" void kernel_launch(void* const* d_in, const int* in_sizes, int n_in,
                              void* d_out, int out_size, void* d_ws, size_t ws_size,
                              hipStream_t stream) {
  const float* x     = (const float*)d_in[0];
  const float* theta = (const float*)d_in[1];
  const float* W1    = (const float*)d_in[2];
  const float* b1    = (const float*)d_in[3];
  const float* W2    = (const float*)d_in[4];
  const float* b2    = (const float*)d_in[5];
  float* out = (float*)d_out;

  char* ws = (char*)d_ws;
  unsigned short* W2b = (unsigned short*)ws;                    // 2 MB
  unsigned short* Hb  = (unsigned short*)(ws + (2u << 20));     // 64 MB

  k_cvt_w2<<<(EMBED * FFN) / (256 * 8), 256, 0, stream>>>(W2, W2b);
  k_phase1<<<NTOK / 16, 256, 0, stream>>>(x, theta, W1, b1, Hb);
  k_gemm<<<(NTOK / BM) * (EMBED / BN), 256, 0, stream>>>(Hb, W2b, b2, out);
}